// Round 4
// baseline (10241.074 us; speedup 1.0000x reference)
//
#include <hip/hip_runtime.h>

#define TT 512
#define BH 65536            // B*H elements (64*1024)
#define NBLK 256

typedef unsigned short u16;
typedef __attribute__((ext_vector_type(8))) __bf16 bf16x8;
typedef __attribute__((ext_vector_type(4))) float f32x4;
typedef __attribute__((ext_vector_type(4))) float float4_t;

// workspace byte offsets
#define WS_XBF   0ull
#define WS_H1    67108864ull                 // x_bf16: 512*64*1024*2 B
#define WS_H2    (WS_H1 + 262144ull)         // 2 slots * 64*1024 * 2 B
#define WS_FLAGS (WS_H2 + 262144ull)         // 256 blocks * 32 ints (128 B apart)
#define WS_REL   (WS_FLAGS + 32768ull)       // release word, own line

// B fragments stored pre-swizzled in MFMA order: 4 arrays [32 kc][64 lane][8 u16]
// LB0 @0, LB1 @16384, LH0 @32768, LH1 @49152 (u16 units). 128 KiB total.
#define LDS_BYTES 131072

__device__ __forceinline__ u16 f2bf(float f) {
  unsigned u = __builtin_bit_cast(unsigned, f);
  u += 0x7fffu + ((u >> 16) & 1u);
  return (u16)(u >> 16);
}

__device__ __forceinline__ float sigm(float x) { return 1.0f / (1.0f + __expf(-x)); }
__device__ __forceinline__ float tanh_fast(float x) { return 1.0f - 2.0f / (__expf(2.0f * x) + 1.0f); }

__global__ __launch_bounds__(256) void cast_x_kernel(const float* __restrict__ x, u16* __restrict__ xbf) {
  unsigned i = (blockIdx.x * 256u + threadIdx.x) * 4u;
  float4_t v = *(const float4_t*)(x + i);
  unsigned p0 = (unsigned)f2bf(v.x) | ((unsigned)f2bf(v.y) << 16);
  unsigned p1 = (unsigned)f2bf(v.z) | ((unsigned)f2bf(v.w) << 16);
  uint2 p; p.x = p0; p.y = p1;
  *(uint2*)(xbf + i) = p;
}

__global__ __launch_bounds__(256) void init_kernel(const float* __restrict__ h0,
                                                   u16* __restrict__ h1s, u16* __restrict__ h2s,
                                                   int* __restrict__ flags, int* __restrict__ rel) {
  unsigned idx = blockIdx.x * 256u + threadIdx.x;   // < 131072
  unsigned l = idx >> 16;
  unsigned pos = idx & 65535u;
  u16* dst = (l == 0 ? h1s : h2s) + BH + pos;       // slot 1 = "h[-1]"
  *dst = f2bf(h0[idx]);                             // end-of-kernel release flushes to L3
  if (idx < 8192) flags[idx] = 0;
  if (idx == 0) rel[0] = 0;
}

// 256 blocks: 0..127 layer0 (step t=it), 128..255 layer1 (step t=it-1).
// Each block: 8 hidden cols -> 32 gate cols, weights LDS-resident, c in regs.
// h exchange: sc1 write-through stores (flag => data at L3) + per-iteration
// agent acquire fence (buffer_inv) + NORMAL cached loads => h broadcast is
// served from per-XCD L2 with full line reuse instead of the L3 fabric.
// INVARIANT for the inv's safety: this kernel never leaves dirty lines in L2
// (all global stores in the loop are agent-scope write-through).
__global__ __launch_bounds__(256, 1) void lstm_kernel(
    const float* __restrict__ Wih, const float* __restrict__ Whh,
    const float* __restrict__ bias, const float* __restrict__ c0,
    const u16* __restrict__ xbf,
    u16* __restrict__ h1s, u16* __restrict__ h2s,
    float* __restrict__ out, int* __restrict__ flags, int* __restrict__ rel)
{
  extern __shared__ __align__(16) char smem_raw[];
  u16* lw = (u16*)smem_raw;
  const int tid = threadIdx.x;
  const int bid = blockIdx.x;
  const int layer = bid >> 7;
  const int lb = bid & 127;
  const int jbase = lb * 8;

  // ---- stage weight slices into LDS (fp32 -> bf16), pre-swizzled into MFMA
  // fragment order: arr[kc][lane][8], lane = q*16 + lnt  (conflict-free reads)
  const float* WihL = Wih + (size_t)layer * 4096 * 1024;
  const float* WhhL = Whh + (size_t)layer * 4096 * 1024;
  for (int idx = tid; idx < 8192; idx += 256) {
    int n = idx >> 8;                       // 0..31 tile row
    int k4 = (idx & 255) * 4;               // element base (4-aligned)
    int gate = n >> 3, jj = n & 7;
    int tile = n >> 4, lnt = n & 15;
    size_t grow = (size_t)(gate * 1024 + jbase + jj) * 1024 + k4;
    float4_t a = *(const float4_t*)(WihL + grow);
    float4_t b = *(const float4_t*)(WhhL + grow);
    int kc = k4 >> 5, q = (k4 & 31) >> 3, e = k4 & 7;   // e in {0,4}
    int di = kc * 512 + q * 128 + lnt * 8 + e;
    u16* d0 = lw + tile * 16384 + di;           // Wih -> LB0/LB1
    u16* d1 = lw + 32768 + tile * 16384 + di;   // Whh -> LH0/LH1
    d0[0] = f2bf(a.x); d0[1] = f2bf(a.y); d0[2] = f2bf(a.z); d0[3] = f2bf(a.w);
    d1[0] = f2bf(b.x); d1[1] = f2bf(b.y); d1[2] = f2bf(b.z); d1[3] = f2bf(b.w);
  }

  const int lane = tid & 63;
  const int w = tid >> 6;                   // wave id: M-tile
  const int q = lane >> 4;                  // quad
  const int ln = lane & 15;
  const int arow = w * 16 + ln;             // batch row for A-frag loads
  const int koff = q * 8;
  const int jj = ln & 7;
  const bool act = ln < 8;                  // epilogue-active lanes
  const int col = jbase + jj;               // hidden column
  const int mrow0 = w * 16 + q * 4;         // C-frag rows mrow0 + r

  const float* bL = bias + layer * 4096;
  const float bn0 = bL[(ln >> 3) * 1024 + jbase + jj];        // i/f bias (col n=ln)
  const float bn1 = bL[(2 + (ln >> 3)) * 1024 + jbase + jj];  // g/o bias (col n=16+ln)

  float c[4];
  {
    const float* c0L = c0 + (size_t)layer * BH;
#pragma unroll
    for (int r = 0; r < 4; ++r) c[r] = c0L[(mrow0 + r) * 1024 + col];
  }

  u16* mySlot = (layer == 0) ? h1s : h2s;
  const size_t OUT_HN = (size_t)TT * BH;
  const size_t OUT_CN = OUT_HN + 2 * BH;

  // per-lane LDS fragment base pointers (linear per wave: lane*16 B)
  const u16* pB0 = lw + lane * 8;           // Wih, N-tile 0 (gates i,f)
  const u16* pB1 = pB0 + 16384;             // Wih, N-tile 1 (gates g,o)
  const u16* pH0 = pB0 + 32768;             // Whh, N-tile 0
  const u16* pH1 = pB0 + 49152;             // Whh, N-tile 1

  __syncthreads();

  for (int it = 0; it <= TT; ++it) {
    const int t = (layer == 0) ? it : (it - 1);
    if (t >= 0 && t < TT) {
      // ---- deep prefetch: ALL A-fragments of both streams into registers.
      // All loads are NORMAL cached loads (L1/L2): coherence is provided by
      // the agent acquire fence executed after the grid barrier below.
      bf16x8 a0[32];
      if (layer == 0) {
        const u16* a0p = xbf + (size_t)t * BH + arow * 1024 + koff;
#pragma unroll
        for (int kc = 0; kc < 32; ++kc) a0[kc] = *(const bf16x8*)(a0p + kc * 32);
      } else {
        const u16* a0p = h1s + (size_t)(t & 1) * BH + arow * 1024 + koff;
#pragma unroll
        for (int kc = 0; kc < 32; ++kc) a0[kc] = *(const bf16x8*)(a0p + kc * 32);
      }
      bf16x8 a1[32];
      {
        const u16* a1p = mySlot + (size_t)((t - 1) & 1) * BH + arow * 1024 + koff;
#pragma unroll
        for (int kc = 0; kc < 32; ++kc) a1[kc] = *(const bf16x8*)(a1p + kc * 32);
      }

      f32x4 acc0 = {0.f, 0.f, 0.f, 0.f};
      f32x4 acc1 = {0.f, 0.f, 0.f, 0.f};
      f32x4 acc2 = {0.f, 0.f, 0.f, 0.f};
      f32x4 acc3 = {0.f, 0.f, 0.f, 0.f};

      // ---- MFMA loop 1: input projection (Wih-side B, stream a0)
#pragma unroll
      for (int kc = 0; kc < 32; ++kc) {
        bf16x8 b0 = *(const bf16x8*)(pB0 + kc * 512);
        bf16x8 b1 = *(const bf16x8*)(pB1 + kc * 512);
        if (kc & 1) {
          acc2 = __builtin_amdgcn_mfma_f32_16x16x32_bf16(a0[kc], b0, acc2, 0, 0, 0);
          acc3 = __builtin_amdgcn_mfma_f32_16x16x32_bf16(a0[kc], b1, acc3, 0, 0, 0);
        } else {
          acc0 = __builtin_amdgcn_mfma_f32_16x16x32_bf16(a0[kc], b0, acc0, 0, 0, 0);
          acc1 = __builtin_amdgcn_mfma_f32_16x16x32_bf16(a0[kc], b1, acc1, 0, 0, 0);
        }
      }
      // ---- MFMA loop 2: recurrent projection (Whh-side B, stream a1)
#pragma unroll
      for (int kc = 0; kc < 32; ++kc) {
        bf16x8 b0 = *(const bf16x8*)(pH0 + kc * 512);
        bf16x8 b1 = *(const bf16x8*)(pH1 + kc * 512);
        if (kc & 1) {
          acc2 = __builtin_amdgcn_mfma_f32_16x16x32_bf16(a1[kc], b0, acc2, 0, 0, 0);
          acc3 = __builtin_amdgcn_mfma_f32_16x16x32_bf16(a1[kc], b1, acc3, 0, 0, 0);
        } else {
          acc0 = __builtin_amdgcn_mfma_f32_16x16x32_bf16(a1[kc], b0, acc0, 0, 0, 0);
          acc1 = __builtin_amdgcn_mfma_f32_16x16x32_bf16(a1[kc], b1, acc1, 0, 0, 0);
        }
      }

      float g0[4], g1[4], f4[4], o4[4];
#pragma unroll
      for (int r = 0; r < 4; ++r) { g0[r] = acc0[r] + acc2[r] + bn0; g1[r] = acc1[r] + acc3[r] + bn1; }
#pragma unroll
      for (int r = 0; r < 4; ++r) { f4[r] = __shfl_down(g0[r], 8); o4[r] = __shfl_down(g1[r], 8); }

      if (act) {
        float hn[4];
#pragma unroll
        for (int r = 0; r < 4; ++r) {
          float iv = sigm(g0[r]);           // cols 0..7   : i
          float fv = sigm(f4[r]);           // cols 8..15  : f (shuffled)
          float gv = tanh_fast(g1[r]);      // cols 16..23 : g
          float ov = sigm(o4[r]);           // cols 24..31 : o (shuffled)
          c[r] = fv * c[r] + iv * gv;
          hn[r] = ov * tanh_fast(c[r]);
        }
        u16* hdst = mySlot + (size_t)(t & 1) * BH;
#pragma unroll
        for (int r = 0; r < 4; ++r)         // write-through to L3 (sc1)
          __hip_atomic_store(&hdst[(mrow0 + r) * 1024 + col], f2bf(hn[r]),
                             __ATOMIC_RELAXED, __HIP_MEMORY_SCOPE_AGENT);
        if (layer == 1) {
          float* od = out + (size_t)t * BH;
#pragma unroll
          for (int r = 0; r < 4; ++r)       // sc1: keep L2 free of dirty lines
            __hip_atomic_store(&od[(mrow0 + r) * 1024 + col], hn[r],
                               __ATOMIC_RELAXED, __HIP_MEMORY_SCOPE_AGENT);
        }
        if (t == TT - 1) {
#pragma unroll
          for (int r = 0; r < 4; ++r) {
            __hip_atomic_store(&out[OUT_HN + (size_t)layer * BH + (mrow0 + r) * 1024 + col],
                               hn[r], __ATOMIC_RELAXED, __HIP_MEMORY_SCOPE_AGENT);
            __hip_atomic_store(&out[OUT_CN + (size_t)layer * BH + (mrow0 + r) * 1024 + col],
                               c[r], __ATOMIC_RELAXED, __HIP_MEMORY_SCOPE_AGENT);
          }
        }
      }
    }

    // ---- grid barrier: flags + release word. sc1 stores are visible at L3
    // once vmcnt retires, which __syncthreads enforces.
    if (it < TT) {
      __syncthreads();
      if (bid == 0) {
        if (tid > 0) {
          while (__hip_atomic_load(&flags[tid * 32], __ATOMIC_RELAXED,
                                   __HIP_MEMORY_SCOPE_AGENT) < it + 1)
            __builtin_amdgcn_s_sleep(1);
        }
        __syncthreads();                    // all arrivals seen
        if (tid == 0)
          __hip_atomic_store(rel, it + 1, __ATOMIC_RELAXED, __HIP_MEMORY_SCOPE_AGENT);
      } else {
        if (tid == 0) {
          __hip_atomic_store(&flags[bid * 32], it + 1, __ATOMIC_RELAXED,
                             __HIP_MEMORY_SCOPE_AGENT);
          while (__hip_atomic_load(rel, __ATOMIC_RELAXED,
                                   __HIP_MEMORY_SCOPE_AGENT) < it + 1)
            __builtin_amdgcn_s_sleep(1);
        }
        __syncthreads();
      }
      // agent acquire: waitcnt + buffer_inv — drops all (clean) L1/L2 copies
      // of the h slots so the normal cached loads above fetch fresh data from
      // the L3 coherence point. Safe: loop body leaves no dirty L2 lines.
      __builtin_amdgcn_fence(__ATOMIC_ACQUIRE, "agent");
    }
  }
}

extern "C" void kernel_launch(void* const* d_in, const int* in_sizes, int n_in,
                              void* d_out, int out_size, void* d_ws, size_t ws_size,
                              hipStream_t stream) {
  const float* x    = (const float*)d_in[0];
  const float* Wih  = (const float*)d_in[1];
  const float* Whh  = (const float*)d_in[2];
  const float* bias = (const float*)d_in[3];
  const float* h0   = (const float*)d_in[4];
  const float* c0   = (const float*)d_in[5];
  float* out = (float*)d_out;
  char* ws = (char*)d_ws;
  u16* xbf  = (u16*)(ws + WS_XBF);
  u16* h1s  = (u16*)(ws + WS_H1);
  u16* h2s  = (u16*)(ws + WS_H2);
  int* flags = (int*)(ws + WS_FLAGS);
  int* rel   = (int*)(ws + WS_REL);

  hipFuncSetAttribute((const void*)lstm_kernel,
                      hipFuncAttributeMaxDynamicSharedMemorySize, LDS_BYTES);

  cast_x_kernel<<<32768, 256, 0, stream>>>(x, xbf);
  init_kernel<<<512, 256, 0, stream>>>(h0, h1s, h2s, flags, rel);
  lstm_kernel<<<NBLK, 256, LDS_BYTES, stream>>>(Wih, Whh, bias, c0, xbf, h1s, h2s,
                                                out, flags, rel);
}

// Round 5
// 7506.335 us; speedup vs baseline: 1.3643x; 1.3643x over previous
//
#include <hip/hip_runtime.h>

#define TT 512
#define BH 65536            // B*H elements (64*1024)
#define NBLK 256

typedef unsigned short u16;
typedef __attribute__((ext_vector_type(8))) __bf16 bf16x8;
typedef __attribute__((ext_vector_type(4))) float f32x4;
typedef __attribute__((ext_vector_type(4))) float float4_t;
typedef __attribute__((ext_vector_type(2))) unsigned long long u64x2;

// workspace byte offsets
#define WS_XBF   0ull
#define WS_H1    67108864ull                 // x_bf16: 512*64*1024*2 B
#define WS_H2    (WS_H1 + 262144ull)         // 2 slots * 64*1024 * 2 B
#define WS_FLAGS (WS_H2 + 262144ull)         // 256 blocks * 32 ints (128 B apart)
#define WS_PFLAG (WS_FLAGS + 32768ull)       // 128 pairs * 32 ints (128 B apart)
#define WS_REL   (WS_PFLAG + 16384ull)       // release word, own line
#define WS_PART  (WS_REL + 256ull)           // 128 pairs * 16 KiB fp32 partials

// Weights in LDS, MFMA-fragment order: per matrix 4 gate-tiles x 16 kc x 64
// lanes x 8 u16 = 64 KiB. Wih @0, Whh @32768 (u16 units). 128 KiB total.
#define LDS_BYTES 131072

__device__ __forceinline__ u16 f2bf(float f) {
  unsigned u = __builtin_bit_cast(unsigned, f);
  u += 0x7fffu + ((u >> 16) & 1u);
  return (u16)(u >> 16);
}

__device__ __forceinline__ float sigm(float x) { return 1.0f / (1.0f + __expf(-x)); }
__device__ __forceinline__ float tanh_fast(float x) { return 1.0f - 2.0f / (__expf(2.0f * x) + 1.0f); }

// 16B coherent read via two 8B agent-scope relaxed loads (global_load_dwordx2
// sc1: bypasses non-coherent L2, reads the L3 coherence point directly)
__device__ __forceinline__ bf16x8 ld8_sc1(const u16* p) {
  u64x2 v;
  v.x = __hip_atomic_load((const unsigned long long*)p,       __ATOMIC_RELAXED, __HIP_MEMORY_SCOPE_AGENT);
  v.y = __hip_atomic_load((const unsigned long long*)(p + 4), __ATOMIC_RELAXED, __HIP_MEMORY_SCOPE_AGENT);
  return __builtin_bit_cast(bf16x8, v);
}

__device__ __forceinline__ unsigned long long pk2(float a, float b) {
  union { float f[2]; unsigned long long u; } v; v.f[0] = a; v.f[1] = b; return v.u;
}

__global__ __launch_bounds__(256) void cast_x_kernel(const float* __restrict__ x, u16* __restrict__ xbf) {
  unsigned i = (blockIdx.x * 256u + threadIdx.x) * 4u;
  float4_t v = *(const float4_t*)(x + i);
  unsigned p0 = (unsigned)f2bf(v.x) | ((unsigned)f2bf(v.y) << 16);
  unsigned p1 = (unsigned)f2bf(v.z) | ((unsigned)f2bf(v.w) << 16);
  uint2 p; p.x = p0; p.y = p1;
  *(uint2*)(xbf + i) = p;
}

__global__ __launch_bounds__(256) void init_kernel(const float* __restrict__ h0,
                                                   u16* __restrict__ h1s, u16* __restrict__ h2s,
                                                   int* __restrict__ flags, int* __restrict__ rel) {
  unsigned idx = blockIdx.x * 256u + threadIdx.x;   // < 131072
  unsigned l = idx >> 16;
  unsigned pos = idx & 65535u;
  u16* dst = (l == 0 ? h1s : h2s) + BH + pos;       // slot 1 = "h[-1]"
  *dst = f2bf(h0[idx]);                             // end-of-kernel release flushes to L3
  if (idx < 12288) flags[idx] = 0;                  // barrier flags + pair flags
  if (idx == 0) rel[0] = 0;
}

// 256 blocks = 2 layers x 64 column-pairs x 2 K-halves.
// Pair p covers hidden cols [p*16, p*16+16); half 0 (primary) owns K [0,512),
// half 1 (secondary) owns K [512,1024). Each block: 64 gate rows x 512 K of
// Wih+Whh in LDS (128 KiB), A-reads halved vs full-K design (MSHR x L3-latency
// bound). Secondary ships fp32 partial acc through L3 (sc1 + pair flag);
// primary adds, applies activations, stores h. Verified sc1 protocol only.
__global__ __launch_bounds__(256, 1) void lstm_kernel(
    const float* __restrict__ Wih, const float* __restrict__ Whh,
    const float* __restrict__ bias, const float* __restrict__ c0,
    const u16* __restrict__ xbf,
    u16* __restrict__ h1s, u16* __restrict__ h2s,
    float* __restrict__ out, int* __restrict__ flags, int* __restrict__ pflags,
    int* __restrict__ rel, char* __restrict__ part)
{
  extern __shared__ __align__(16) char smem_raw[];
  u16* lw = (u16*)smem_raw;
  const int tid = threadIdx.x;
  const int bid = blockIdx.x;
  const int layer = bid >> 7;
  const int lb = bid & 127;
  const int p = lb >> 1;
  const int half = lb & 1;
  const int pg = layer * 64 + p;            // global pair id 0..127
  const int jbase16 = p * 16;               // hidden-column base of the tile
  const int kbase = half * 512;             // K-half owned by this block
  const bool prim = (half == 0);

  // ---- stage weight K-half into LDS (fp32 -> bf16), MFMA fragment order:
  // arr[gate][kc][lane][8], lane = q*16 + lnt, elements k = kc*32 + q*8 + e
  const float* WihL = Wih + (size_t)layer * 4096 * 1024;
  const float* WhhL = Whh + (size_t)layer * 4096 * 1024;
  for (int idx = tid; idx < 8192; idx += 256) {
    int n4 = idx >> 7;                      // 0..63 : gate*16 + lnt
    int k4 = (idx & 127) * 4;               // 0..508
    int gate = n4 >> 4, lnt = n4 & 15;
    size_t grow = (size_t)(gate * 1024 + jbase16 + lnt) * 1024 + kbase + k4;
    float4_t a = *(const float4_t*)(WihL + grow);
    float4_t b = *(const float4_t*)(WhhL + grow);
    int kc = k4 >> 5, q = (k4 & 31) >> 3, e = k4 & 7;   // e in {0,4}
    int di = gate * 8192 + kc * 512 + (q * 16 + lnt) * 8 + e;
    u16* d0 = lw + di;                      // Wih
    u16* d1 = lw + 32768 + di;              // Whh
    d0[0] = f2bf(a.x); d0[1] = f2bf(a.y); d0[2] = f2bf(a.z); d0[3] = f2bf(a.w);
    d1[0] = f2bf(b.x); d1[1] = f2bf(b.y); d1[2] = f2bf(b.z); d1[3] = f2bf(b.w);
  }

  const int lane = tid & 63;
  const int w = tid >> 6;                   // wave id: M-tile (16 batch rows)
  const int q = lane >> 4;                  // quad
  const int ln = lane & 15;
  const int arow = w * 16 + ln;             // batch row for A-frag loads
  const int koff = q * 8;                   // k-element offset within 32-chunk
  const int col16 = jbase16 + ln;           // hidden column (all lanes active)
  const int mrow0 = w * 16 + q * 4;         // C-frag rows mrow0 + r

  // per-lane partial-exchange pointer (lane-for-lane identical on both halves)
  char* pb = part + (size_t)pg * 16384 + (size_t)tid * 64;

  float bn[4];
  float c[4];
  if (prim) {
    const float* bL = bias + layer * 4096;
#pragma unroll
    for (int g = 0; g < 4; ++g) bn[g] = bL[g * 1024 + col16];
    const float* c0L = c0 + (size_t)layer * BH;
#pragma unroll
    for (int r = 0; r < 4; ++r) c[r] = c0L[(mrow0 + r) * 1024 + col16];
  }

  u16* mySlot = (layer == 0) ? h1s : h2s;
  const size_t OUT_HN = (size_t)TT * BH;
  const size_t OUT_CN = OUT_HN + 2 * BH;

  // per-lane LDS fragment base pointers (linear per wave: lane*16 B)
  const u16* pW = lw + lane * 8;            // Wih tiles: + gate*8192 + kc*512
  const u16* pH = pW + 32768;               // Whh tiles

  __syncthreads();

  for (int it = 0; it <= TT; ++it) {
    const int t = (layer == 0) ? it : (it - 1);
    if (t >= 0 && t < TT) {
      // ---- prefetch all A-fragments of both streams (K-half) into registers
      bf16x8 a0[16];
      if (layer == 0) {                     // x: read-only, cacheable
        const u16* a0p = xbf + (size_t)t * BH + arow * 1024 + kbase + koff;
#pragma unroll
        for (int kc = 0; kc < 16; ++kc) a0[kc] = *(const bf16x8*)(a0p + kc * 32);
      } else {                              // h1 from layer0: coherent
        const u16* a0p = h1s + (size_t)(t & 1) * BH + arow * 1024 + kbase + koff;
#pragma unroll
        for (int kc = 0; kc < 16; ++kc) a0[kc] = ld8_sc1(a0p + kc * 32);
      }
      bf16x8 a1[16];
      {
        const u16* a1p = mySlot + (size_t)((t - 1) & 1) * BH + arow * 1024 + kbase + koff;
#pragma unroll
        for (int kc = 0; kc < 16; ++kc) a1[kc] = ld8_sc1(a1p + kc * 32);
      }

      f32x4 acc[4];
#pragma unroll
      for (int g = 0; g < 4; ++g) acc[g] = (f32x4){0.f, 0.f, 0.f, 0.f};

      // ---- input projection (Wih-side), then recurrent (Whh-side)
#pragma unroll
      for (int kc = 0; kc < 16; ++kc) {
#pragma unroll
        for (int g = 0; g < 4; ++g) {
          bf16x8 b = *(const bf16x8*)(pW + g * 8192 + kc * 512);
          acc[g] = __builtin_amdgcn_mfma_f32_16x16x32_bf16(a0[kc], b, acc[g], 0, 0, 0);
        }
      }
#pragma unroll
      for (int kc = 0; kc < 16; ++kc) {
#pragma unroll
        for (int g = 0; g < 4; ++g) {
          bf16x8 b = *(const bf16x8*)(pH + g * 8192 + kc * 512);
          acc[g] = __builtin_amdgcn_mfma_f32_16x16x32_bf16(a1[kc], b, acc[g], 0, 0, 0);
        }
      }

      if (!prim) {
        // ---- secondary: ship fp32 partial (16 floats/lane) via L3
#pragma unroll
        for (int g = 0; g < 4; ++g) {
          __hip_atomic_store((unsigned long long*)(pb + g * 16),
                             pk2(acc[g][0], acc[g][1]),
                             __ATOMIC_RELAXED, __HIP_MEMORY_SCOPE_AGENT);
          __hip_atomic_store((unsigned long long*)(pb + g * 16 + 8),
                             pk2(acc[g][2], acc[g][3]),
                             __ATOMIC_RELAXED, __HIP_MEMORY_SCOPE_AGENT);
        }
        __syncthreads();                    // all waves' stores vmcnt-retired
        if (tid == 0)
          __hip_atomic_store(&pflags[pg * 32], t + 1,
                             __ATOMIC_RELAXED, __HIP_MEMORY_SCOPE_AGENT);
      } else {
        // ---- primary: wait for partner partial, add, epilogue
        if (tid == 0) {
          while (__hip_atomic_load(&pflags[pg * 32], __ATOMIC_RELAXED,
                                   __HIP_MEMORY_SCOPE_AGENT) < t + 1)
            __builtin_amdgcn_s_sleep(1);
        }
        __syncthreads();
        float gg[4][4];
#pragma unroll
        for (int g = 0; g < 4; ++g) {
          unsigned long long v0 = __hip_atomic_load((const unsigned long long*)(pb + g * 16),
                                                    __ATOMIC_RELAXED, __HIP_MEMORY_SCOPE_AGENT);
          unsigned long long v1 = __hip_atomic_load((const unsigned long long*)(pb + g * 16 + 8),
                                                    __ATOMIC_RELAXED, __HIP_MEMORY_SCOPE_AGENT);
          union { unsigned long long u; float f[2]; } x0, x1;
          x0.u = v0; x1.u = v1;
          gg[g][0] = acc[g][0] + x0.f[0] + bn[g];
          gg[g][1] = acc[g][1] + x0.f[1] + bn[g];
          gg[g][2] = acc[g][2] + x1.f[0] + bn[g];
          gg[g][3] = acc[g][3] + x1.f[1] + bn[g];
        }
        float hn[4];
#pragma unroll
        for (int r = 0; r < 4; ++r) {
          float iv = sigm(gg[0][r]);
          float fv = sigm(gg[1][r]);
          float gv = tanh_fast(gg[2][r]);
          float ov = sigm(gg[3][r]);
          c[r] = fv * c[r] + iv * gv;
          hn[r] = ov * tanh_fast(c[r]);
        }
        u16* hdst = mySlot + (size_t)(t & 1) * BH;
#pragma unroll
        for (int r = 0; r < 4; ++r)         // write-through to L3 (sc1)
          __hip_atomic_store(&hdst[(mrow0 + r) * 1024 + col16], f2bf(hn[r]),
                             __ATOMIC_RELAXED, __HIP_MEMORY_SCOPE_AGENT);
        if (layer == 1) {
          float* od = out + (size_t)t * BH;
#pragma unroll
          for (int r = 0; r < 4; ++r) od[(mrow0 + r) * 1024 + col16] = hn[r];
        }
        if (t == TT - 1) {
#pragma unroll
          for (int r = 0; r < 4; ++r) {
            out[OUT_HN + (size_t)layer * BH + (mrow0 + r) * 1024 + col16] = hn[r];
            out[OUT_CN + (size_t)layer * BH + (mrow0 + r) * 1024 + col16] = c[r];
          }
        }
      }
    }

    // ---- grid barrier: flags + release word; NO agent fences. sc1 stores are
    // visible at L3 once vmcnt retires, which __syncthreads enforces.
    if (it < TT) {
      __syncthreads();
      if (bid == 0) {
        if (tid > 0) {
          while (__hip_atomic_load(&flags[tid * 32], __ATOMIC_RELAXED,
                                   __HIP_MEMORY_SCOPE_AGENT) < it + 1)
            __builtin_amdgcn_s_sleep(1);
        }
        __syncthreads();                    // all arrivals seen
        if (tid == 0)
          __hip_atomic_store(rel, it + 1, __ATOMIC_RELAXED, __HIP_MEMORY_SCOPE_AGENT);
      } else {
        if (tid == 0) {
          __hip_atomic_store(&flags[bid * 32], it + 1, __ATOMIC_RELAXED,
                             __HIP_MEMORY_SCOPE_AGENT);
          while (__hip_atomic_load(rel, __ATOMIC_RELAXED,
                                   __HIP_MEMORY_SCOPE_AGENT) < it + 1)
            __builtin_amdgcn_s_sleep(1);
        }
        __syncthreads();
      }
      // compiler-reorder guard only (workgroup scope: waitcnt, no cache ops)
      __builtin_amdgcn_fence(__ATOMIC_ACQUIRE, "workgroup");
    }
  }
}

extern "C" void kernel_launch(void* const* d_in, const int* in_sizes, int n_in,
                              void* d_out, int out_size, void* d_ws, size_t ws_size,
                              hipStream_t stream) {
  const float* x    = (const float*)d_in[0];
  const float* Wih  = (const float*)d_in[1];
  const float* Whh  = (const float*)d_in[2];
  const float* bias = (const float*)d_in[3];
  const float* h0   = (const float*)d_in[4];
  const float* c0   = (const float*)d_in[5];
  float* out = (float*)d_out;
  char* ws = (char*)d_ws;
  u16* xbf   = (u16*)(ws + WS_XBF);
  u16* h1s   = (u16*)(ws + WS_H1);
  u16* h2s   = (u16*)(ws + WS_H2);
  int* flags = (int*)(ws + WS_FLAGS);
  int* pflags= (int*)(ws + WS_PFLAG);
  int* rel   = (int*)(ws + WS_REL);
  char* part = (char*)(ws + WS_PART);

  hipFuncSetAttribute((const void*)lstm_kernel,
                      hipFuncAttributeMaxDynamicSharedMemorySize, LDS_BYTES);

  cast_x_kernel<<<32768, 256, 0, stream>>>(x, xbf);
  init_kernel<<<512, 256, 0, stream>>>(h0, h1s, h2s, flags, rel);
  lstm_kernel<<<NBLK, 256, LDS_BYTES, stream>>>(Wih, Whh, bias, c0, xbf, h1s, h2s,
                                                out, flags, pflags, rel, part);
}